// Round 10
// baseline (654.983 us; speedup 1.0000x reference)
//
#include <hip/hip_runtime.h>

#define NP 2048
#define BTOT 8
#define BN_TOT 16384
#define KC 16
#define NTILE 32  // NP/64
#define NEG_INF (-__builtin_inff())

typedef __attribute__((ext_vector_type(8))) short short8;
typedef __attribute__((ext_vector_type(4))) float f32x4;

// ---------------- bf16 split helpers ----------------
__device__ __forceinline__ unsigned short bf16_rne(float x) {
  unsigned u = __float_as_uint(x);
  u += 0x7FFFu + ((u >> 16) & 1u);
  return (unsigned short)(u >> 16);
}
__device__ __forceinline__ void split2(float x, unsigned short& h, unsigned short& l) {
  h = bf16_rne(x);
  float hf = __uint_as_float((unsigned)h << 16);
  l = bf16_rne(x - hf);
}

// ---------------- symmetric pairwise score GEMM + group-max epilogue ----------------
// R6-proven 256-thr/4x4 inner loop. Upper-triangular pairs (bi<=bj):
// pd[i][j]=2dot-sq_j; bi!=bj also pd[j][i]=2dot-sq_i.  NEW: per-row maxima of
// 16-column groups -> gmax[row][128] (i-side groups along j; j-side along i).
// grid (528, 1, cnt_batches)
__global__ __launch_bounds__(256) void dist_gemm(const float* __restrict__ X, int lda, int K,
                                                 const float* __restrict__ sq,
                                                 float* __restrict__ pd,
                                                 float* __restrict__ gmax, int batch0) {
  int bz = blockIdx.z;
  const float* Xb = X + (size_t)(batch0 + bz) * NP * lda;
  const float* sqb = sq + (size_t)(batch0 + bz) * NP;
  float* pdb = pd + (size_t)bz * NP * NP;
  float* gmb = gmax + (size_t)bz * NP * 128;
  int rem = blockIdx.x, bi = 0;
  while (rem >= NTILE - bi) { rem -= NTILE - bi; ++bi; }
  int bj = bi + rem;
  int i0 = bi * 64, j0 = bj * 64;
  __shared__ float At[KC][68];
  __shared__ float Bt[KC][68];
  int t = threadIdx.x;
  int tx = t & 15, ty = t >> 4, wv = t >> 6;
  int lk = t & 15, lr = t >> 4;
  float acc[4][4] = {};
  for (int k0 = 0; k0 < K; k0 += KC) {
    int kk = k0 + lk;
    bool kv = kk < K;
#pragma unroll
    for (int u = 0; u < 4; ++u) {
      int r = lr + u * 16;
      At[lk][r] = kv ? Xb[(size_t)(i0 + r) * lda + kk] : 0.f;
      Bt[lk][r] = kv ? Xb[(size_t)(j0 + r) * lda + kk] : 0.f;
    }
    __syncthreads();
#pragma unroll
    for (int q = 0; q < KC; ++q) {
      float4 a4 = *(const float4*)&At[q][ty * 4];
      float4 b4 = *(const float4*)&Bt[q][tx * 4];
      float a[4] = {a4.x, a4.y, a4.z, a4.w};
      float bv[4] = {b4.x, b4.y, b4.z, b4.w};
#pragma unroll
      for (int ii = 0; ii < 4; ++ii)
#pragma unroll
        for (int jj = 0; jj < 4; ++jj)
          acc[ii][jj] = fmaf(a[ii], bv[jj], acc[ii][jj]);
    }
    __syncthreads();
  }
  float4 sqj4 = *(const float4*)&sqb[j0 + tx * 4];
  float gmI[4];
#pragma unroll
  for (int ii = 0; ii < 4; ++ii) {
    int i = i0 + ty * 4 + ii;
    float4 o;
    o.x = 2.f * acc[ii][0] - sqj4.x;
    o.y = 2.f * acc[ii][1] - sqj4.y;
    o.z = 2.f * acc[ii][2] - sqj4.z;
    o.w = 2.f * acc[ii][3] - sqj4.w;
    *(float4*)&pdb[(size_t)i * NP + j0 + tx * 4] = o;
    gmI[ii] = fmaxf(fmaxf(o.x, o.y), fmaxf(o.z, o.w));
  }
  // i-side group max: reduce over tx%4 (adjacent lanes)
#pragma unroll
  for (int ii = 0; ii < 4; ++ii) {
    gmI[ii] = fmaxf(gmI[ii], __shfl_xor(gmI[ii], 1, 64));
    gmI[ii] = fmaxf(gmI[ii], __shfl_xor(gmI[ii], 2, 64));
  }
  if ((tx & 3) == 0) {
#pragma unroll
    for (int ii = 0; ii < 4; ++ii)
      gmb[(size_t)(i0 + ty * 4 + ii) * 128 + bj * 4 + (tx >> 2)] = gmI[ii];
  }
  if (bi != bj) {
    float4 sqi4 = *(const float4*)&sqb[i0 + ty * 4];
    float sqi[4] = {sqi4.x, sqi4.y, sqi4.z, sqi4.w};
    float gmJ[4];
#pragma unroll
    for (int jj = 0; jj < 4; ++jj) {
      int j = j0 + tx * 4 + jj;
      float4 o;
      o.x = 2.f * acc[0][jj] - sqi[0];
      o.y = 2.f * acc[1][jj] - sqi[1];
      o.z = 2.f * acc[2][jj] - sqi[2];
      o.w = 2.f * acc[3][jj] - sqi[3];
      *(float4*)&pdb[(size_t)j * NP + i0 + ty * 4] = o;
      gmJ[jj] = fmaxf(fmaxf(o.x, o.y), fmaxf(o.z, o.w));
    }
    // j-side group max: reduce over ty%4 (lane stride 16 within wave)
#pragma unroll
    for (int jj = 0; jj < 4; ++jj) {
      gmJ[jj] = fmaxf(gmJ[jj], __shfl_xor(gmJ[jj], 16, 64));
      gmJ[jj] = fmaxf(gmJ[jj], __shfl_xor(gmJ[jj], 32, 64));
    }
    if ((t & 63) < 16) {
#pragma unroll
      for (int jj = 0; jj < 4; ++jj)
        gmb[(size_t)(j0 + tx * 4 + jj) * 128 + bi * 4 + wv] = gmJ[jj];
    }
  }
}

// ---------------- shared top-16 selection (per-wave) ----------------
template <typename JM>
__device__ __forceinline__ void select16(const float (&v)[32], int lane, float* svw,
                                         int* sjw, int* out, int jb, JM jmap) {
  float lmax = v[0];
#pragma unroll
  for (int t = 1; t < 32; ++t) lmax = fmaxf(lmax, v[t]);
  int rank = 0;
  for (int s = 0; s < 64; ++s) {
    float o = __shfl(lmax, s, 64);
    rank += (o > lmax) || (o == lmax && s < lane);
  }
  unsigned long long m15 = __ballot(rank == 15);
  float T0 = __shfl(lmax, (int)__builtin_ctzll(m15), 64);

  unsigned long long lowmask = (1ull << lane) - 1ull;
  unsigned keepmask = 0u;
  int base = 0;
#pragma unroll
  for (int t = 0; t < 32; ++t) {
    bool keep = (v[t] >= T0);
    unsigned long long mk = __ballot(keep);
    if (keep) {
      keepmask |= (1u << t);
      int pos = base + (int)__popcll(mk & lowmask);
      if (pos < 256) { svw[pos] = v[t]; sjw[pos] = jmap(t); }
    }
    base += (int)__popcll(mk);
  }
  int cnt = base;

  if (cnt <= 64) {
    __threadfence_block();
    float mv = NEG_INF;
    int mj = 1 << 30;
    if (lane < cnt) { mv = svw[lane]; mj = sjw[lane]; }
    int rk = 0;
    for (int s = 0; s < 64; ++s) {
      float ov = __shfl(mv, s, 64);
      int oj = __shfl(mj, s, 64);
      rk += (ov > mv) || (ov == mv && oj < mj);
    }
    if (lane < cnt && rk < 16) out[rk] = jb + mj;
    return;
  }

  if (cnt <= 256) {
    __threadfence_block();
    for (int r = 0; r < 16; ++r) {
      float lbv = NEG_INF;
      int lbj = 1 << 30, lbp = -1;
      for (int i = lane; i < cnt; i += 64) {
        float cv = svw[i];
        int cj = sjw[i];
        if (cv > lbv || (cv == lbv && cj < lbj)) { lbv = cv; lbj = cj; lbp = i; }
      }
      float bv = lbv;
      int bj = lbj;
#pragma unroll
      for (int off = 32; off > 0; off >>= 1) {
        float ov = __shfl_xor(bv, off, 64);
        int oj = __shfl_xor(bj, off, 64);
        if (ov > bv || (ov == bv && oj < bj)) { bv = ov; bj = oj; }
      }
      if (lane == 0) out[r] = jb + bj;
      if (lbp >= 0 && lbj == bj) svw[lbp] = NEG_INF;
      __threadfence_block();
    }
    return;
  }

  {  // register-mask fallback (pathological ties)
    unsigned avail = keepmask;
    for (int r = 0; r < 16; ++r) {
      float bv = NEG_INF;
      int bj = 1 << 30, bt = -1;
      unsigned am = avail;
      while (am) {
        int t = __builtin_ctz(am);
        am &= am - 1;
        float vv = v[t];
        int jj = jmap(t);
        if (vv > bv || (vv == bv && jj < bj)) { bv = vv; bj = jj; bt = t; }
      }
      float gv = bv;
      int gj = bj;
#pragma unroll
      for (int off = 32; off > 0; off >>= 1) {
        float ov = __shfl_xor(gv, off, 64);
        int oj = __shfl_xor(gj, off, 64);
        if (ov > gv || (ov == gv && oj < gj)) { gv = ov; gj = oj; }
      }
      if (lane == 0) out[r] = jb + gj;
      if (bt >= 0 && bj == gj) avail &= ~(1u << bt);
    }
  }
}

// full-row selection (fallback path; identical to the R9-proven topk body)
__device__ __forceinline__ void topk_full_row(const float* __restrict__ prow, int lane,
                                              float* svw, int* sjw, int* out, int jb) {
  float v[32];
#pragma unroll
  for (int u = 0; u < 8; ++u) {
    float4 q = *(const float4*)&prow[u * 256 + (lane << 2)];
    v[u * 4 + 0] = q.x;
    v[u * 4 + 1] = q.y;
    v[u * 4 + 2] = q.z;
    v[u * 4 + 3] = q.w;
  }
  select16(v, lane, svw, sjw, out, jb,
           [lane](int t) { return ((t >> 2) << 8) + (lane << 2) + (t & 3); });
}

// ---------------- top-16 per row: group-max filter + sparse gather ----------------
// G16 = exact 16th-largest of the row's 128 group maxima. Lossless filter:
// >=16 groups have max >= G16 => true 16th value T16 >= G16; any value < G16
// is strictly < T16 -> never in the top-16 set (even under ties).
__global__ __launch_bounds__(256) void topk_kernel(const float* __restrict__ pd,
                                                   const float* __restrict__ gmax,
                                                   int* __restrict__ idx_out, int batch0) {
  __shared__ float sv[4][256];
  __shared__ int sj[4][256];
  __shared__ int gl[4][128];
  int wave = threadIdx.x >> 6, lane = threadIdx.x & 63;
  int row = blockIdx.x * 4 + wave;  // chunk-local row
  const float* prow = pd + (size_t)row * NP;
  const float* gmr = gmax + (size_t)row * 128;
  int grow = batch0 * NP + row;
  int jb = (grow >> 11) << 11;
  int* out = idx_out + (size_t)grow * 16;

  float gm0 = gmr[lane], gm1 = gmr[lane + 64];
  // exact rank of both values among all 128 (val desc, pos asc)
  int r0 = 0, r1 = 0;
  for (int s = 0; s < 64; ++s) {
    float o0 = __shfl(gm0, s, 64);
    float o1 = __shfl(gm1, s, 64);
    r0 += (o0 > gm0) || (o0 == gm0 && s < lane);
    r0 += (o1 > gm0);                       // pos s+64 > lane: tie -> mine
    r1 += (o0 >= gm1);                      // pos s < lane+64: tie -> other
    r1 += (o1 > gm1) || (o1 == gm1 && s < lane);
  }
  float G16;
  unsigned long long b0 = __ballot(r0 == 15);
  if (b0)
    G16 = __shfl(gm0, (int)__builtin_ctzll(b0), 64);
  else {
    unsigned long long b1 = __ballot(r1 == 15);
    G16 = __shfl(gm1, (int)__builtin_ctzll(b1), 64);
  }

  // compact surviving group ids
  unsigned long long lowmask = (1ull << lane) - 1ull;
  unsigned long long k0 = __ballot(gm0 >= G16);
  unsigned long long k1 = __ballot(gm1 >= G16);
  int c0 = (int)__popcll(k0);
  if (gm0 >= G16) gl[wave][(int)__popcll(k0 & lowmask)] = lane;
  if (gm1 >= G16) gl[wave][c0 + (int)__popcll(k1 & lowmask)] = lane + 64;
  int gcnt = c0 + (int)__popcll(k1);
  __threadfence_block();

  if (gcnt > 32) {  // rare: too many candidate groups -> proven full-row path
    topk_full_row(prow, lane, sv[wave], sj[wave], out, jb);
    return;
  }

  // gather surviving groups (4 lanes per group), filter v >= G16 into sv/sj
  int cnt = 0;
  for (int bg = 0; bg < gcnt; bg += 16) {
    int gi = bg + (lane >> 2);
    bool act = gi < gcnt;
    int g = act ? gl[wave][gi] : 0;
    float4 q = *(const float4*)&prow[g * 16 + (lane & 3) * 4];
    float qa[4] = {q.x, q.y, q.z, q.w};
#pragma unroll
    for (int t = 0; t < 4; ++t) {
      bool keep = act && (qa[t] >= G16);
      unsigned long long mk = __ballot(keep);
      if (keep) {
        int pos = cnt + (int)__popcll(mk & lowmask);
        if (pos < 256) {
          sv[wave][pos] = qa[t];
          sj[wave][pos] = g * 16 + (lane & 3) * 4 + t;
        }
      }
      cnt += (int)__popcll(mk);
    }
  }
  if (cnt > 256) {  // pathological ties -> proven full-row path
    topk_full_row(prow, lane, sv[wave], sj[wave], out, jb);
    return;
  }
  __threadfence_block();

  if (cnt <= 64) {
    float mv = NEG_INF;
    int mj = 1 << 30;
    if (lane < cnt) { mv = sv[wave][lane]; mj = sj[wave][lane]; }
    int rk = 0;
    for (int s = 0; s < 64; ++s) {
      float ov = __shfl(mv, s, 64);
      int oj = __shfl(mj, s, 64);
      rk += (ov > mv) || (ov == mv && oj < mj);
    }
    if (lane < cnt && rk < 16) out[rk] = jb + mj;
    return;
  }
  for (int r = 0; r < 16; ++r) {
    float lbv = NEG_INF;
    int lbj = 1 << 30, lbp = -1;
    for (int i = lane; i < cnt; i += 64) {
      float cv = sv[wave][i];
      int cj = sj[wave][i];
      if (cv > lbv || (cv == lbv && cj < lbj)) { lbv = cv; lbj = cj; lbp = i; }
    }
    float bv = lbv;
    int bj = lbj;
#pragma unroll
    for (int off = 32; off > 0; off >>= 1) {
      float ov = __shfl_xor(bv, off, 64);
      int oj = __shfl_xor(bj, off, 64);
      if (ov > bv || (ov == bv && oj < bj)) { bv = ov; bj = oj; }
    }
    if (lane == 0) out[r] = jb + bj;
    if (lbp >= 0 && lbj == bj) sv[wave][lbp] = NEG_INF;
    __threadfence_block();
  }
}

// ---------------- layer-1 fused: C=3 scores from LDS + top-16 ----------------
__global__ __launch_bounds__(256) void dist3_topk(const float* __restrict__ x,
                                                  int* __restrict__ idx_out) {
  __shared__ float4 xs4[NP];
  __shared__ float sv[4][256];
  __shared__ int sj[4][256];
  int wave = threadIdx.x >> 6, lane = threadIdx.x & 63;
  int b = blockIdx.x >> 7;
  int row0 = (blockIdx.x & 127) * 16;
  const float* xb = x + (size_t)b * NP * 3;
  for (int n = threadIdx.x; n < NP; n += 256) {
    float a0 = xb[3 * n], a1 = xb[3 * n + 1], a2 = xb[3 * n + 2];
    xs4[n] = make_float4(a0, a1, a2, a0 * a0 + a1 * a1 + a2 * a2);
  }
  __syncthreads();
  int jb = b << 11;
  for (int rr = 0; rr < 4; ++rr) {
    int row = row0 + wave * 4 + rr;
    float4 c = xs4[row];
    float v[32];
#pragma unroll
    for (int t = 0; t < 32; ++t) {
      int j = lane + t * 64;
      float4 p = xs4[j];
      float dot = c.x * p.x + c.y * p.y + c.z * p.z;
      v[t] = 2.f * dot - p.w;
    }
    select16(v, lane, sv[wave], sj[wave], idx_out + (size_t)(jb + row) * 16, jb,
             [lane](int t) { return lane + t * 64; });
  }
}

// ---------------- point-wise GEMM: Z = X@Wtop (z=0), Y = X@Wbot (z=1) ----------------
__global__ __launch_bounds__(256) void feat_gemm(const float* __restrict__ A, int lda, int K,
                                                 const float* __restrict__ W, int D,
                                                 float* __restrict__ outT,
                                                 float* __restrict__ outB) {
  const float* Wz = W + (size_t)blockIdx.z * K * D;
  float* o = blockIdx.z ? outB : outT;
  int n0 = blockIdx.x * 64, m0 = blockIdx.y * 64;
  __shared__ float At[KC][68];
  __shared__ float Bt[KC][68];
  int t = threadIdx.x;
  int tx = t & 15, ty = t >> 4;
  float acc[4][4] = {};
  for (int k0 = 0; k0 < K; k0 += KC) {
    {
      int lk = t & 15, lr = t >> 4;
      int kk = k0 + lk;
      bool kv = kk < K;
#pragma unroll
      for (int u = 0; u < 4; ++u) {
        int r = lr + u * 16;
        At[lk][r] = kv ? A[(size_t)(m0 + r) * lda + kk] : 0.f;
      }
      int n = t & 63, kq0 = t >> 6;
#pragma unroll
      for (int u = 0; u < 4; ++u) {
        int kq = kq0 + u * 4;
        int kg = k0 + kq;
        Bt[kq][n] = (kg < K) ? Wz[(size_t)kg * D + n0 + n] : 0.f;
      }
    }
    __syncthreads();
#pragma unroll
    for (int q = 0; q < KC; ++q) {
      float4 a4 = *(const float4*)&At[q][ty * 4];
      float4 b4 = *(const float4*)&Bt[q][tx * 4];
      float a[4] = {a4.x, a4.y, a4.z, a4.w};
      float bv[4] = {b4.x, b4.y, b4.z, b4.w};
#pragma unroll
      for (int ii = 0; ii < 4; ++ii)
#pragma unroll
        for (int jj = 0; jj < 4; ++jj)
          acc[ii][jj] = fmaf(a[ii], bv[jj], acc[ii][jj]);
    }
    __syncthreads();
  }
#pragma unroll
  for (int ii = 0; ii < 4; ++ii) {
    float4 o4 = make_float4(acc[ii][0], acc[ii][1], acc[ii][2], acc[ii][3]);
    *(float4*)&o[(size_t)(m0 + ty * 4 + ii) * D + n0 + tx * 4] = o4;
  }
}

// ---------------- gather + BN + ReLU, fused epilogue (R9-proven) ----------------
__global__ __launch_bounds__(256) void gather_bn_relu(const float* __restrict__ ZT,
                                                      const float* __restrict__ YB,
                                                      const int* __restrict__ idx, int D,
                                                      const float* __restrict__ g,
                                                      const float* __restrict__ bta,
                                                      const float* __restrict__ mu,
                                                      const float* __restrict__ va,
                                                      float* __restrict__ X5,
                                                      unsigned short* __restrict__ X5h,
                                                      unsigned short* __restrict__ X5l,
                                                      float* __restrict__ sqout, int coff) {
  __shared__ int nb[16];
  __shared__ float red[256];
  int bn = blockIdx.x, d = threadIdx.x;
  if (d < 16) nb[d] = idx[(size_t)bn * 16 + d];
  __syncthreads();
  float mx = NEG_INF;
#pragma unroll
  for (int j = 0; j < 16; ++j) mx = fmaxf(mx, YB[(size_t)nb[j] * D + d]);
  float h = ZT[(size_t)bn * D + d] + mx;
  float s = g[d] / sqrtf(va[d] + 1e-3f);
  float val = fmaxf((h - mu[d]) * s + bta[d], 0.f);
  size_t oi = (size_t)bn * 512 + coff + d;
  X5[oi] = val;
  unsigned short vh, vl;
  split2(val, vh, vl);
  X5h[oi] = vh;
  X5l[oi] = vl;
  red[d] = val * val;
  __syncthreads();
  for (int st = blockDim.x >> 1; st > 0; st >>= 1) {
    if (d < st) red[d] += red[d + st];
    __syncthreads();
  }
  if (d == 0) sqout[bn] = red[0];
}

// ---------------- W5^T split: Wt[n][k] = split(W5[k][n]) ----------------
__global__ __launch_bounds__(256) void w5t_split(const float* __restrict__ W5,
                                                 unsigned short* __restrict__ Wh,
                                                 unsigned short* __restrict__ Wl) {
  int n = blockIdx.x;
  for (int k = threadIdx.x; k < 512; k += 256) {
    unsigned short h, l;
    split2(W5[(size_t)k * 512 + n], h, l);
    Wh[(size_t)n * 512 + k] = h;
    Wl[(size_t)n * 512 + k] = l;
  }
}

// ---------------- final GEMM via split-bf16 MFMA, no LDS (R6-verified) ----------------
__global__ __launch_bounds__(256) void final_mfma(const unsigned short* __restrict__ Ah,
                                                  const unsigned short* __restrict__ Al,
                                                  const unsigned short* __restrict__ Bh,
                                                  const unsigned short* __restrict__ Bl,
                                                  const float* __restrict__ g,
                                                  const float* __restrict__ bta,
                                                  const float* __restrict__ mu,
                                                  const float* __restrict__ va,
                                                  float* __restrict__ out) {
  int tid = threadIdx.x;
  int wave = tid >> 6, lane = tid & 63;
  int wm = wave >> 1, wn = wave & 1;
  int ln = lane & 15, quad = lane >> 4;
  int m_base = blockIdx.y * 128 + wm * 64;
  int n_base = blockIdx.x * 128 + wn * 64;

  f32x4 acc[4][4];
#pragma unroll
  for (int i = 0; i < 4; ++i)
#pragma unroll
    for (int j = 0; j < 4; ++j) acc[i][j] = (f32x4){0.f, 0.f, 0.f, 0.f};

  size_t aoff[4], boff[4];
#pragma unroll
  for (int t = 0; t < 4; ++t) {
    aoff[t] = (size_t)(m_base + t * 16 + ln) * 512 + quad * 8;
    boff[t] = (size_t)(n_base + t * 16 + ln) * 512 + quad * 8;
  }

  short8 cAh[4], cAl[4], cBh[4], cBl[4];
#pragma unroll
  for (int t = 0; t < 4; ++t) {
    cAh[t] = *(const short8*)(Ah + aoff[t]);
    cAl[t] = *(const short8*)(Al + aoff[t]);
    cBh[t] = *(const short8*)(Bh + boff[t]);
    cBl[t] = *(const short8*)(Bl + boff[t]);
  }

  for (int kk = 0; kk < 16; ++kk) {
    short8 nAh[4], nAl[4], nBh[4], nBl[4];
    if (kk < 15) {
      int ko = (kk + 1) * 32;
#pragma unroll
      for (int t = 0; t < 4; ++t) {
        nAh[t] = *(const short8*)(Ah + aoff[t] + ko);
        nAl[t] = *(const short8*)(Al + aoff[t] + ko);
        nBh[t] = *(const short8*)(Bh + boff[t] + ko);
        nBl[t] = *(const short8*)(Bl + boff[t] + ko);
      }
    }
#pragma unroll
    for (int tm = 0; tm < 4; ++tm)
#pragma unroll
      for (int tn = 0; tn < 4; ++tn) {
        acc[tm][tn] = __builtin_amdgcn_mfma_f32_16x16x32_bf16(cAh[tm], cBh[tn],
                                                              acc[tm][tn], 0, 0, 0);
        acc[tm][tn] = __builtin_amdgcn_mfma_f32_16x16x32_bf16(cAh[tm], cBl[tn],
                                                              acc[tm][tn], 0, 0, 0);
        acc[tm][tn] = __builtin_amdgcn_mfma_f32_16x16x32_bf16(cAl[tm], cBh[tn],
                                                              acc[tm][tn], 0, 0, 0);
      }
    if (kk < 15) {
#pragma unroll
      for (int t = 0; t < 4; ++t) {
        cAh[t] = nAh[t];
        cAl[t] = nAl[t];
        cBh[t] = nBh[t];
        cBl[t] = nBl[t];
      }
    }
  }

#pragma unroll
  for (int tn = 0; tn < 4; ++tn) {
    int col = n_base + tn * 16 + ln;
    float s = g[col] / sqrtf(va[col] + 1e-3f);
    float tc = bta[col] - mu[col] * s;
#pragma unroll
    for (int tm = 0; tm < 4; ++tm) {
      int mrow = m_base + tm * 16 + quad * 4;
#pragma unroll
      for (int r = 0; r < 4; ++r) {
        float val = acc[tm][tn][r] * s + tc;
        out[(size_t)(mrow + r) * 512 + col] = fmaxf(val, 0.f);
      }
    }
  }
}

extern "C" void kernel_launch(void* const* d_in, const int* in_sizes, int n_in,
                              void* d_out, int out_size, void* d_ws, size_t ws_size,
                              hipStream_t stream) {
  const float* x = (const float*)d_in[0];
  const float *W[5], *g[5], *bt[5], *mu[5], *va[5];
  for (int j = 0; j < 5; ++j) {
    W[j] = (const float*)d_in[1 + j * 5 + 0];
    g[j] = (const float*)d_in[1 + j * 5 + 1];
    bt[j] = (const float*)d_in[1 + j * 5 + 2];
    mu[j] = (const float*)d_in[1 + j * 5 + 3];
    va[j] = (const float*)d_in[1 + j * 5 + 4];
  }
  char* p = (char*)d_ws;
  float* X5 = (float*)p; p += (size_t)BN_TOT * 512 * 4;   // concat [x1|x2|x3|x4]
  float* ZT = (float*)p; p += (size_t)BN_TOT * 256 * 4;   // X @ Wtop
  float* YB = (float*)p; p += (size_t)BN_TOT * 256 * 4;   // X @ Wbot
  int* idx = (int*)p;    p += (size_t)BN_TOT * 16 * 4;    // global neighbor rows
  float* sq = (float*)p; p += (size_t)BN_TOT * 4;
  unsigned short* X5h = (unsigned short*)p; p += (size_t)BN_TOT * 512 * 2;
  unsigned short* X5l = (unsigned short*)p; p += (size_t)BN_TOT * 512 * 2;
  unsigned short* W5h = (unsigned short*)p; p += (size_t)512 * 512 * 2;
  unsigned short* W5l = (unsigned short*)p; p += (size_t)512 * 512 * 2;
  float* gmax = (float*)p; p += (size_t)BTOT * NP * 128 * 4;  // 8 MB group maxima
  float* pd = (float*)p;
  size_t used = (size_t)(p - (char*)d_ws);
  size_t pdcap = (ws_size > used) ? (ws_size - used) / ((size_t)NP * NP * 4) : 0;
  int nb = (int)(pdcap < 1 ? 1 : (pdcap > (size_t)BTOT ? (size_t)BTOT : pdcap));

  w5t_split<<<512, 256, 0, stream>>>(W[4], W5h, W5l);

  struct Blk { const float* A; int lda, C, D, coff, w; };
  Blk blks[4] = {
      {x, 3, 3, 64, 0, 0},
      {X5 + 0, 512, 64, 64, 64, 1},
      {X5 + 64, 512, 64, 128, 128, 2},
      {X5 + 128, 512, 128, 256, 256, 3},
  };
  for (int q = 0; q < 4; ++q) {
    Blk& B = blks[q];
    if (q == 0) {
      dist3_topk<<<1024, 256, 0, stream>>>(x, idx);
    } else {
      // sq for this layer's input was produced by the previous layer's gather
      for (int b0 = 0; b0 < BTOT; b0 += nb) {
        int cnt = (BTOT - b0 < nb) ? (BTOT - b0) : nb;
        dist_gemm<<<dim3(NTILE * (NTILE + 1) / 2, 1, cnt), 256, 0, stream>>>(
            B.A, B.lda, B.C, sq, pd, gmax, b0);
        topk_kernel<<<cnt * NP / 4, 256, 0, stream>>>(pd, gmax, idx, b0);
      }
    }
    feat_gemm<<<dim3(B.D / 64, BN_TOT / 64, 2), 256, 0, stream>>>(
        B.A, B.lda, B.C, W[B.w], B.D, ZT, YB);
    gather_bn_relu<<<BN_TOT, B.D, 0, stream>>>(ZT, YB, idx, B.D, g[B.w], bt[B.w], mu[B.w],
                                               va[B.w], X5, X5h, X5l, sq, B.coff);
  }
  final_mfma<<<dim3(4, 128), 256, 0, stream>>>(X5h, X5l, W5h, W5l, g[4], bt[4], mu[4],
                                               va[4], (float*)d_out);
}

// Round 11
// 615.193 us; speedup vs baseline: 1.0647x; 1.0647x over previous
//
#include <hip/hip_runtime.h>

#define NP 2048
#define BTOT 8
#define BN_TOT 16384
#define KC 16
#define NTILE 32  // NP/64
#define NEG_INF (-__builtin_inff())

typedef __attribute__((ext_vector_type(8))) short short8;
typedef __attribute__((ext_vector_type(4))) float f32x4;

// ---------------- bf16 split helpers ----------------
__device__ __forceinline__ unsigned short bf16_rne(float x) {
  unsigned u = __float_as_uint(x);
  u += 0x7FFFu + ((u >> 16) & 1u);
  return (unsigned short)(u >> 16);
}
__device__ __forceinline__ void split2(float x, unsigned short& h, unsigned short& l) {
  h = bf16_rne(x);
  float hf = __uint_as_float((unsigned)h << 16);
  l = bf16_rne(x - hf);
}

// ---------------- symmetric pairwise score GEMM (R9-proven: 256 thr, 4x4) ----------------
// Upper-triangular tile pairs (bi<=bj); pd[i][j]=2dot-sq_j; bi!=bj also pd[j][i]=2dot-sq_i.
// grid (528, 1, cnt_batches)
__global__ __launch_bounds__(256) void dist_gemm(const float* __restrict__ X, int lda, int K,
                                                 const float* __restrict__ sq,
                                                 float* __restrict__ pd, int batch0) {
  int bz = blockIdx.z;
  const float* Xb = X + (size_t)(batch0 + bz) * NP * lda;
  const float* sqb = sq + (size_t)(batch0 + bz) * NP;
  float* pdb = pd + (size_t)bz * NP * NP;
  int rem = blockIdx.x, bi = 0;
  while (rem >= NTILE - bi) { rem -= NTILE - bi; ++bi; }
  int bj = bi + rem;
  int i0 = bi * 64, j0 = bj * 64;
  __shared__ float At[KC][68];
  __shared__ float Bt[KC][68];
  int t = threadIdx.x;
  int tx = t & 15, ty = t >> 4;
  int lk = t & 15, lr = t >> 4;
  float acc[4][4] = {};
  for (int k0 = 0; k0 < K; k0 += KC) {
    int kk = k0 + lk;
    bool kv = kk < K;
#pragma unroll
    for (int u = 0; u < 4; ++u) {
      int r = lr + u * 16;
      At[lk][r] = kv ? Xb[(size_t)(i0 + r) * lda + kk] : 0.f;
      Bt[lk][r] = kv ? Xb[(size_t)(j0 + r) * lda + kk] : 0.f;
    }
    __syncthreads();
#pragma unroll
    for (int q = 0; q < KC; ++q) {
      float4 a4 = *(const float4*)&At[q][ty * 4];
      float4 b4 = *(const float4*)&Bt[q][tx * 4];
      float a[4] = {a4.x, a4.y, a4.z, a4.w};
      float bv[4] = {b4.x, b4.y, b4.z, b4.w};
#pragma unroll
      for (int ii = 0; ii < 4; ++ii)
#pragma unroll
        for (int jj = 0; jj < 4; ++jj)
          acc[ii][jj] = fmaf(a[ii], bv[jj], acc[ii][jj]);
    }
    __syncthreads();
  }
  float4 sqj4 = *(const float4*)&sqb[j0 + tx * 4];
#pragma unroll
  for (int ii = 0; ii < 4; ++ii) {
    int i = i0 + ty * 4 + ii;
    float4 o;
    o.x = 2.f * acc[ii][0] - sqj4.x;
    o.y = 2.f * acc[ii][1] - sqj4.y;
    o.z = 2.f * acc[ii][2] - sqj4.z;
    o.w = 2.f * acc[ii][3] - sqj4.w;
    *(float4*)&pdb[(size_t)i * NP + j0 + tx * 4] = o;
  }
  if (bi != bj) {
    float4 sqi4 = *(const float4*)&sqb[i0 + ty * 4];
#pragma unroll
    for (int jj = 0; jj < 4; ++jj) {
      int j = j0 + tx * 4 + jj;
      float4 o;
      o.x = 2.f * acc[0][jj] - sqi4.x;
      o.y = 2.f * acc[1][jj] - sqi4.y;
      o.z = 2.f * acc[2][jj] - sqi4.z;
      o.w = 2.f * acc[3][jj] - sqi4.w;
      *(float4*)&pdb[(size_t)j * NP + i0 + ty * 4] = o;
    }
  }
}

// ---------------- shared top-16 selection (per-wave) ----------------
template <typename JM>
__device__ __forceinline__ void select16(const float (&v)[32], int lane, float* svw,
                                         int* sjw, int* out, int jb, JM jmap) {
  float lmax = v[0];
#pragma unroll
  for (int t = 1; t < 32; ++t) lmax = fmaxf(lmax, v[t]);
  int rank = 0;
  for (int s = 0; s < 64; ++s) {
    float o = __shfl(lmax, s, 64);
    rank += (o > lmax) || (o == lmax && s < lane);
  }
  unsigned long long m15 = __ballot(rank == 15);
  float T0 = __shfl(lmax, (int)__builtin_ctzll(m15), 64);

  unsigned long long lowmask = (1ull << lane) - 1ull;
  unsigned keepmask = 0u;
  int base = 0;
#pragma unroll
  for (int t = 0; t < 32; ++t) {
    bool keep = (v[t] >= T0);
    unsigned long long mk = __ballot(keep);
    if (keep) {
      keepmask |= (1u << t);
      int pos = base + (int)__popcll(mk & lowmask);
      if (pos < 256) { svw[pos] = v[t]; sjw[pos] = jmap(t); }
    }
    base += (int)__popcll(mk);
  }
  int cnt = base;

  if (cnt <= 64) {
    __threadfence_block();
    float mv = NEG_INF;
    int mj = 1 << 30;
    if (lane < cnt) { mv = svw[lane]; mj = sjw[lane]; }
    int rk = 0;
    for (int s = 0; s < 64; ++s) {
      float ov = __shfl(mv, s, 64);
      int oj = __shfl(mj, s, 64);
      rk += (ov > mv) || (ov == mv && oj < mj);
    }
    if (lane < cnt && rk < 16) out[rk] = jb + mj;
    return;
  }

  if (cnt <= 256) {
    __threadfence_block();
    for (int r = 0; r < 16; ++r) {
      float lbv = NEG_INF;
      int lbj = 1 << 30, lbp = -1;
      for (int i = lane; i < cnt; i += 64) {
        float cv = svw[i];
        int cj = sjw[i];
        if (cv > lbv || (cv == lbv && cj < lbj)) { lbv = cv; lbj = cj; lbp = i; }
      }
      float bv = lbv;
      int bj = lbj;
#pragma unroll
      for (int off = 32; off > 0; off >>= 1) {
        float ov = __shfl_xor(bv, off, 64);
        int oj = __shfl_xor(bj, off, 64);
        if (ov > bv || (ov == bv && oj < bj)) { bv = ov; bj = oj; }
      }
      if (lane == 0) out[r] = jb + bj;
      if (lbp >= 0 && lbj == bj) svw[lbp] = NEG_INF;
      __threadfence_block();
    }
    return;
  }

  {  // register-mask fallback (pathological ties)
    unsigned avail = keepmask;
    for (int r = 0; r < 16; ++r) {
      float bv = NEG_INF;
      int bj = 1 << 30, bt = -1;
      unsigned am = avail;
      while (am) {
        int t = __builtin_ctz(am);
        am &= am - 1;
        float vv = v[t];
        int jj = jmap(t);
        if (vv > bv || (vv == bv && jj < bj)) { bv = vv; bj = jj; bt = t; }
      }
      float gv = bv;
      int gj = bj;
#pragma unroll
      for (int off = 32; off > 0; off >>= 1) {
        float ov = __shfl_xor(gv, off, 64);
        int oj = __shfl_xor(gj, off, 64);
        if (ov > gv || (ov == gv && oj < gj)) { gv = ov; gj = oj; }
      }
      if (lane == 0) out[r] = jb + gj;
      if (bt >= 0 && bj == gj) avail &= ~(1u << bt);
    }
  }
}

// ---------------- top-16 per row over materialized pd (R9-proven) ----------------
__global__ __launch_bounds__(256) void topk_kernel(const float* __restrict__ pd,
                                                   int* __restrict__ idx_out, int batch0) {
  __shared__ float sv[4][256];
  __shared__ int sj[4][256];
  int wave = threadIdx.x >> 6, lane = threadIdx.x & 63;
  int row = blockIdx.x * 4 + wave;
  const float* prow = pd + (size_t)row * NP;
  int grow = batch0 * NP + row;
  int jb = (grow >> 11) << 11;
  float v[32];
#pragma unroll
  for (int u = 0; u < 8; ++u) {
    float4 q = *(const float4*)&prow[u * 256 + (lane << 2)];
    v[u * 4 + 0] = q.x;
    v[u * 4 + 1] = q.y;
    v[u * 4 + 2] = q.z;
    v[u * 4 + 3] = q.w;
  }
  select16(v, lane, sv[wave], sj[wave], idx_out + (size_t)grow * 16, jb,
           [lane](int t) { return ((t >> 2) << 8) + (lane << 2) + (t & 3); });
}

// ---------------- layer-1 fused: C=3 scores from LDS + top-16 ----------------
__global__ __launch_bounds__(256) void dist3_topk(const float* __restrict__ x,
                                                  int* __restrict__ idx_out) {
  __shared__ float4 xs4[NP];
  __shared__ float sv[4][256];
  __shared__ int sj[4][256];
  int wave = threadIdx.x >> 6, lane = threadIdx.x & 63;
  int b = blockIdx.x >> 7;
  int row0 = (blockIdx.x & 127) * 16;
  const float* xb = x + (size_t)b * NP * 3;
  for (int n = threadIdx.x; n < NP; n += 256) {
    float a0 = xb[3 * n], a1 = xb[3 * n + 1], a2 = xb[3 * n + 2];
    xs4[n] = make_float4(a0, a1, a2, a0 * a0 + a1 * a1 + a2 * a2);
  }
  __syncthreads();
  int jb = b << 11;
  for (int rr = 0; rr < 4; ++rr) {
    int row = row0 + wave * 4 + rr;
    float4 c = xs4[row];
    float v[32];
#pragma unroll
    for (int t = 0; t < 32; ++t) {
      int j = lane + t * 64;
      float4 p = xs4[j];
      float dot = c.x * p.x + c.y * p.y + c.z * p.z;
      v[t] = 2.f * dot - p.w;
    }
    select16(v, lane, sv[wave], sj[wave], idx_out + (size_t)(jb + row) * 16, jb,
             [lane](int t) { return lane + t * 64; });
  }
}

// ---------------- point-wise GEMM: Z = X@Wtop (z=0), Y = X@Wbot (z=1) ----------------
__global__ __launch_bounds__(256) void feat_gemm(const float* __restrict__ A, int lda, int K,
                                                 const float* __restrict__ W, int D,
                                                 float* __restrict__ outT,
                                                 float* __restrict__ outB) {
  const float* Wz = W + (size_t)blockIdx.z * K * D;
  float* o = blockIdx.z ? outB : outT;
  int n0 = blockIdx.x * 64, m0 = blockIdx.y * 64;
  __shared__ float At[KC][68];
  __shared__ float Bt[KC][68];
  int t = threadIdx.x;
  int tx = t & 15, ty = t >> 4;
  float acc[4][4] = {};
  for (int k0 = 0; k0 < K; k0 += KC) {
    {
      int lk = t & 15, lr = t >> 4;
      int kk = k0 + lk;
      bool kv = kk < K;
#pragma unroll
      for (int u = 0; u < 4; ++u) {
        int r = lr + u * 16;
        At[lk][r] = kv ? A[(size_t)(m0 + r) * lda + kk] : 0.f;
      }
      int n = t & 63, kq0 = t >> 6;
#pragma unroll
      for (int u = 0; u < 4; ++u) {
        int kq = kq0 + u * 4;
        int kg = k0 + kq;
        Bt[kq][n] = (kg < K) ? Wz[(size_t)kg * D + n0 + n] : 0.f;
      }
    }
    __syncthreads();
#pragma unroll
    for (int q = 0; q < KC; ++q) {
      float4 a4 = *(const float4*)&At[q][ty * 4];
      float4 b4 = *(const float4*)&Bt[q][tx * 4];
      float a[4] = {a4.x, a4.y, a4.z, a4.w};
      float bv[4] = {b4.x, b4.y, b4.z, b4.w};
#pragma unroll
      for (int ii = 0; ii < 4; ++ii)
#pragma unroll
        for (int jj = 0; jj < 4; ++jj)
          acc[ii][jj] = fmaf(a[ii], bv[jj], acc[ii][jj]);
    }
    __syncthreads();
  }
#pragma unroll
  for (int ii = 0; ii < 4; ++ii) {
    float4 o4 = make_float4(acc[ii][0], acc[ii][1], acc[ii][2], acc[ii][3]);
    *(float4*)&o[(size_t)(m0 + ty * 4 + ii) * D + n0 + tx * 4] = o4;
  }
}

// ---------------- gather + BN + ReLU, fused epilogue; 256-thr blocks ----------------
// Each block handles P = 256/D points (4 for D=64, 2 for D=128, 1 for D=256),
// fixing the tiny-workgroup underutilization for D<256. Per-point sq reduction
// uses the same stride order as the R9 version -> bit-identical sq.
// grid BN_TOT*D/256.
__global__ __launch_bounds__(256) void gather_bn_relu(const float* __restrict__ ZT,
                                                      const float* __restrict__ YB,
                                                      const int* __restrict__ idx, int D,
                                                      const float* __restrict__ g,
                                                      const float* __restrict__ bta,
                                                      const float* __restrict__ mu,
                                                      const float* __restrict__ va,
                                                      float* __restrict__ X5,
                                                      unsigned short* __restrict__ X5h,
                                                      unsigned short* __restrict__ X5l,
                                                      float* __restrict__ sqout, int coff) {
  __shared__ int nb[4][16];
  __shared__ float red[256];
  int P = 256 / D;
  int t = threadIdx.x;
  int pt = t / D, d = t - pt * D;
  int bn = blockIdx.x * P + pt;
  if (t < 16 * P) {
    int pp = t >> 4, ii = t & 15;
    nb[pp][ii] = idx[(size_t)(blockIdx.x * P + pp) * 16 + ii];
  }
  __syncthreads();
  float mx = NEG_INF;
#pragma unroll
  for (int j = 0; j < 16; ++j) mx = fmaxf(mx, YB[(size_t)nb[pt][j] * D + d]);
  float h = ZT[(size_t)bn * D + d] + mx;
  float s = g[d] / sqrtf(va[d] + 1e-3f);
  float val = fmaxf((h - mu[d]) * s + bta[d], 0.f);
  size_t oi = (size_t)bn * 512 + coff + d;
  X5[oi] = val;
  unsigned short vh, vl;
  split2(val, vh, vl);
  X5h[oi] = vh;
  X5l[oi] = vl;
  // per-point sq reduction, same stride order as R9 (bit-identical)
  red[t] = val * val;
  __syncthreads();
  for (int st = D >> 1; st > 0; st >>= 1) {
    if (d < st) red[pt * D + d] += red[pt * D + d + st];
    __syncthreads();
  }
  if (d == 0) sqout[bn] = red[pt * D];
}

// ---------------- W5^T split: Wt[n][k] = split(W5[k][n]) ----------------
__global__ __launch_bounds__(256) void w5t_split(const float* __restrict__ W5,
                                                 unsigned short* __restrict__ Wh,
                                                 unsigned short* __restrict__ Wl) {
  int n = blockIdx.x;
  for (int k = threadIdx.x; k < 512; k += 256) {
    unsigned short h, l;
    split2(W5[(size_t)k * 512 + n], h, l);
    Wh[(size_t)n * 512 + k] = h;
    Wl[(size_t)n * 512 + k] = l;
  }
}

// ---------------- final GEMM via split-bf16 MFMA, no LDS (R6-verified) ----------------
__global__ __launch_bounds__(256) void final_mfma(const unsigned short* __restrict__ Ah,
                                                  const unsigned short* __restrict__ Al,
                                                  const unsigned short* __restrict__ Bh,
                                                  const unsigned short* __restrict__ Bl,
                                                  const float* __restrict__ g,
                                                  const float* __restrict__ bta,
                                                  const float* __restrict__ mu,
                                                  const float* __restrict__ va,
                                                  float* __restrict__ out) {
  int tid = threadIdx.x;
  int wave = tid >> 6, lane = tid & 63;
  int wm = wave >> 1, wn = wave & 1;
  int ln = lane & 15, quad = lane >> 4;
  int m_base = blockIdx.y * 128 + wm * 64;
  int n_base = blockIdx.x * 128 + wn * 64;

  f32x4 acc[4][4];
#pragma unroll
  for (int i = 0; i < 4; ++i)
#pragma unroll
    for (int j = 0; j < 4; ++j) acc[i][j] = (f32x4){0.f, 0.f, 0.f, 0.f};

  size_t aoff[4], boff[4];
#pragma unroll
  for (int t = 0; t < 4; ++t) {
    aoff[t] = (size_t)(m_base + t * 16 + ln) * 512 + quad * 8;
    boff[t] = (size_t)(n_base + t * 16 + ln) * 512 + quad * 8;
  }

  short8 cAh[4], cAl[4], cBh[4], cBl[4];
#pragma unroll
  for (int t = 0; t < 4; ++t) {
    cAh[t] = *(const short8*)(Ah + aoff[t]);
    cAl[t] = *(const short8*)(Al + aoff[t]);
    cBh[t] = *(const short8*)(Bh + boff[t]);
    cBl[t] = *(const short8*)(Bl + boff[t]);
  }

  for (int kk = 0; kk < 16; ++kk) {
    short8 nAh[4], nAl[4], nBh[4], nBl[4];
    if (kk < 15) {
      int ko = (kk + 1) * 32;
#pragma unroll
      for (int t = 0; t < 4; ++t) {
        nAh[t] = *(const short8*)(Ah + aoff[t] + ko);
        nAl[t] = *(const short8*)(Al + aoff[t] + ko);
        nBh[t] = *(const short8*)(Bh + boff[t] + ko);
        nBl[t] = *(const short8*)(Bl + boff[t] + ko);
      }
    }
#pragma unroll
    for (int tm = 0; tm < 4; ++tm)
#pragma unroll
      for (int tn = 0; tn < 4; ++tn) {
        acc[tm][tn] = __builtin_amdgcn_mfma_f32_16x16x32_bf16(cAh[tm], cBh[tn],
                                                              acc[tm][tn], 0, 0, 0);
        acc[tm][tn] = __builtin_amdgcn_mfma_f32_16x16x32_bf16(cAh[tm], cBl[tn],
                                                              acc[tm][tn], 0, 0, 0);
        acc[tm][tn] = __builtin_amdgcn_mfma_f32_16x16x32_bf16(cAl[tm], cBh[tn],
                                                              acc[tm][tn], 0, 0, 0);
      }
    if (kk < 15) {
#pragma unroll
      for (int t = 0; t < 4; ++t) {
        cAh[t] = nAh[t];
        cAl[t] = nAl[t];
        cBh[t] = nBh[t];
        cBl[t] = nBl[t];
      }
    }
  }

#pragma unroll
  for (int tn = 0; tn < 4; ++tn) {
    int col = n_base + tn * 16 + ln;
    float s = g[col] / sqrtf(va[col] + 1e-3f);
    float tc = bta[col] - mu[col] * s;
#pragma unroll
    for (int tm = 0; tm < 4; ++tm) {
      int mrow = m_base + tm * 16 + quad * 4;
#pragma unroll
      for (int r = 0; r < 4; ++r) {
        float val = acc[tm][tn][r] * s + tc;
        out[(size_t)(mrow + r) * 512 + col] = fmaxf(val, 0.f);
      }
    }
  }
}

extern "C" void kernel_launch(void* const* d_in, const int* in_sizes, int n_in,
                              void* d_out, int out_size, void* d_ws, size_t ws_size,
                              hipStream_t stream) {
  const float* x = (const float*)d_in[0];
  const float *W[5], *g[5], *bt[5], *mu[5], *va[5];
  for (int j = 0; j < 5; ++j) {
    W[j] = (const float*)d_in[1 + j * 5 + 0];
    g[j] = (const float*)d_in[1 + j * 5 + 1];
    bt[j] = (const float*)d_in[1 + j * 5 + 2];
    mu[j] = (const float*)d_in[1 + j * 5 + 3];
    va[j] = (const float*)d_in[1 + j * 5 + 4];
  }
  char* p = (char*)d_ws;
  float* X5 = (float*)p; p += (size_t)BN_TOT * 512 * 4;   // concat [x1|x2|x3|x4]
  float* ZT = (float*)p; p += (size_t)BN_TOT * 256 * 4;   // X @ Wtop
  float* YB = (float*)p; p += (size_t)BN_TOT * 256 * 4;   // X @ Wbot
  int* idx = (int*)p;    p += (size_t)BN_TOT * 16 * 4;    // global neighbor rows
  float* sq = (float*)p; p += (size_t)BN_TOT * 4;
  unsigned short* X5h = (unsigned short*)p; p += (size_t)BN_TOT * 512 * 2;
  unsigned short* X5l = (unsigned short*)p; p += (size_t)BN_TOT * 512 * 2;
  unsigned short* W5h = (unsigned short*)p; p += (size_t)512 * 512 * 2;
  unsigned short* W5l = (unsigned short*)p; p += (size_t)512 * 512 * 2;
  float* pd = (float*)p;
  size_t used = (size_t)(p - (char*)d_ws);
  size_t pdcap = (ws_size > used) ? (ws_size - used) / ((size_t)NP * NP * 4) : 0;
  int nb = (int)(pdcap < 1 ? 1 : (pdcap > (size_t)BTOT ? (size_t)BTOT : pdcap));

  w5t_split<<<512, 256, 0, stream>>>(W[4], W5h, W5l);

  struct Blk { const float* A; int lda, C, D, coff, w; };
  Blk blks[4] = {
      {x, 3, 3, 64, 0, 0},
      {X5 + 0, 512, 64, 64, 64, 1},
      {X5 + 64, 512, 64, 128, 128, 2},
      {X5 + 128, 512, 128, 256, 256, 3},
  };
  for (int q = 0; q < 4; ++q) {
    Blk& B = blks[q];
    if (q == 0) {
      dist3_topk<<<1024, 256, 0, stream>>>(x, idx);
    } else {
      // sq for this layer's input was produced by the previous layer's gather
      for (int b0 = 0; b0 < BTOT; b0 += nb) {
        int cnt = (BTOT - b0 < nb) ? (BTOT - b0) : nb;
        dist_gemm<<<dim3(NTILE * (NTILE + 1) / 2, 1, cnt), 256, 0, stream>>>(
            B.A, B.lda, B.C, sq, pd, b0);
        topk_kernel<<<cnt * NP / 4, 256, 0, stream>>>(pd, idx, b0);
      }
    }
    feat_gemm<<<dim3(B.D / 64, BN_TOT / 64, 2), 256, 0, stream>>>(
        B.A, B.lda, B.C, W[B.w], B.D, ZT, YB);
    gather_bn_relu<<<BN_TOT * B.D / 256, 256, 0, stream>>>(
        ZT, YB, idx, B.D, g[B.w], bt[B.w], mu[B.w], va[B.w], X5, X5h, X5l, sq, B.coff);
  }
  final_mfma<<<dim3(4, 128), 256, 0, stream>>>(X5h, X5l, W5h, W5l, g[4], bt[4], mu[4],
                                               va[4], (float*)d_out);
}